// Round 15
// baseline (373.202 us; speedup 1.0000x reference)
//
#include <hip/hip_runtime.h>
#include <math.h>

#define BB 64
#define TT 1024
#define DD 32
#define GG 128   // 4*D
#define VOCABN 10000
#define QLEN 100

typedef short short8 __attribute__((ext_vector_type(8)));   // 8 bf16 in 4 VGPRs
typedef float floatx4 __attribute__((ext_vector_type(4)));
typedef float floatx2 __attribute__((ext_vector_type(2)));
typedef unsigned short u16;

__device__ __forceinline__ float fsig(float x) {
    return __builtin_amdgcn_rcpf(1.0f + __expf(-x));
}
__device__ __forceinline__ float readlane_f(float v, int l) {
    return __int_as_float(__builtin_amdgcn_readlane(__float_as_int(v), l));
}
__device__ __forceinline__ u16 f2bf_rne(float x) {
    unsigned u = __float_as_uint(x);
    u += 0x7FFF + ((u >> 16) & 1);
    return (u16)(u >> 16);
}
__device__ __forceinline__ float bf2f(u16 s) {
    return __uint_as_float(((unsigned)s) << 16);
}
// packed fma: one v_pk_fma_f32 for the {a,b}-gate pair. IEEE fma per half ->
// bit-exact vs two fmaf.
__device__ __forceinline__ floatx2 fma2(float s, floatx2 w, floatx2 acc) {
    return __builtin_elementwise_fma((floatx2){s, s}, w, acc);
}

// ---------------------------------------------------------------------------
// Kernel 1: LSTM scan — R28 version (measured 237 µs, VGPR 132). DO NOT
// reshape (R23/R24: any other shape spills the weight arrays). pk_fma dots +
// permlane32_swap + cvt fused into producer slack; hout stores deleted.
// R32 delta: queue block additionally zeroes the per-batch ycnt counters
// (used by k_attn's fused last-block tail; kernel-boundary ordering makes
// this visible before any attn block runs).
// ---------------------------------------------------------------------------
#define UU 8
__global__
__attribute__((amdgpu_flat_work_group_size(128, 128)))
__attribute__((amdgpu_waves_per_eu(1, 1)))
void k_lstm_scan(const int* __restrict__ ids,
                 const float* __restrict__ emb,
                 const float* __restrict__ klstm,
                 const float* __restrict__ bias,
                 const float* __restrict__ rk,
                 u16* __restrict__ hh, u16* __restrict__ hl,
                 u16* __restrict__ th, u16* __restrict__ tl,
                 int* __restrict__ list,
                 int* __restrict__ ycnt,
                 float* __restrict__ outq) {
    const int b = blockIdx.x;
    const int tid = threadIdx.x;
    const int wv = tid >> 6;   // wave 0 consumer / wave 1 producer+cvt
    const int l = tid & 63;
    if (b >= BB) {
        if (wv != 0) return;
        if (l < BB) ycnt[l] = 0;   // reset tail counters for this launch
        // ---- fused zero-index queue (single wave, no barriers) ----
        const int4* v4 = (const int4*)ids;
        const int C4 = (BB * TT) / 4 / 64;
        const int b4 = l * C4;
        int cnt = 0;
#pragma unroll 4
        for (int i = 0; i < C4; ++i) {
            int4 v = v4[b4 + i];
            cnt += (v.x == 0 || (unsigned)v.x >= VOCABN);
            cnt += (v.y == 0 || (unsigned)v.y >= VOCABN);
            cnt += (v.z == 0 || (unsigned)v.z >= VOCABN);
            cnt += (v.w == 0 || (unsigned)v.w >= VOCABN);
        }
        int scan = cnt;
#pragma unroll
        for (int o = 1; o < 64; o <<= 1) {
            int nn = __shfl_up(scan, o);
            if (l >= o) scan += nn;
        }
        const int total = __shfl(scan, 63);
        int off = scan - cnt;
        const int base = l * (C4 * 4);
#pragma unroll 4
        for (int i = 0; i < C4; ++i) {
            int4 v = v4[b4 + i];
            if (v.x == 0 || (unsigned)v.x >= VOCABN) list[off++] = base + 4 * i;
            if (v.y == 0 || (unsigned)v.y >= VOCABN) list[off++] = base + 4 * i + 1;
            if (v.z == 0 || (unsigned)v.z >= VOCABN) list[off++] = base + 4 * i + 2;
            if (v.w == 0 || (unsigned)v.w >= VOCABN) list[off++] = base + 4 * i + 3;
        }
        __threadfence();
        const int Kc = total < QLEN ? total : QLEN;
        for (int t = l; t < QLEN; t += 64) {
            float ii = -1.0f, jj = -1.0f;
            if (t >= QLEN - Kc) {
                int pos = list[total - QLEN + t];
                ii = (float)(pos >> 10);
                jj = (float)(pos & (TT - 1));
            }
            outq[2 * t] = ii;
            outq[2 * t + 1] = jj;
        }
        return;
    }

    __shared__ float ring[2][UU][GG];                    // 8 KB xg ring
    __shared__ __align__(16) float hring[2][UU][DD];     // 2 KB h ring (cvt)
    const int* idsb = ids + b * TT;

    if (wv == 1) {
        // ---------- producer: xg 8 tokens ahead + cvt of chunk-1 -----------
        const int ja = l, jb = l + 64;
        floatx2 kp[DD];
#pragma unroll
        for (int d2 = 0; d2 < DD; ++d2)
            kp[d2] = (floatx2){klstm[d2 * GG + ja], klstm[d2 * GG + jb]};
        const floatx2 bj = (floatx2){bias[ja], bias[jb]};
        const int dd = l & 31;
        // cvt lane mappings
        const int u_r = l >> 3, dc = (l & 7) * 4;        // row side: 8B u16 runs
        const int d_c = l & 31, ug = (l >> 5) * 4;       // col side: 4 consecutive t
        u16* hhb = hh + (size_t)b * TT * DD;
        u16* hlb = hl + (size_t)b * TT * DD;
        u16* thb = th + (size_t)b * DD * TT;
        u16* tlb = tl + (size_t)b * DD * TT;

#define PROD_TOKEN(SEL, U, EV)                                               \
        {                                                                    \
            floatx2 z0 = bj;                                                 \
            floatx2 z1 = {0.f, 0.f}, z2 = {0.f, 0.f}, z3 = {0.f, 0.f};       \
            _Pragma("unroll")                                                \
            for (int k = 0; k < DD; k += 4) {                                \
                float e0 = readlane_f(EV, k);                                \
                float e1 = readlane_f(EV, k + 1);                            \
                float e2 = readlane_f(EV, k + 2);                            \
                float e3 = readlane_f(EV, k + 3);                            \
                z0 = fma2(e0, kp[k], z0);                                    \
                z1 = fma2(e1, kp[k + 1], z1);                                \
                z2 = fma2(e2, kp[k + 2], z2);                                \
                z3 = fma2(e3, kp[k + 3], z3);                                \
            }                                                                \
            floatx2 zf = (z0 + z1) + (z2 + z3);                              \
            ring[SEL][U][ja] = zf.x;                                         \
            ring[SEL][U][jb] = zf.y;                                         \
        }

        // convert chunk starting at token TC0 from hring[HSEL]
#define CVT_CHUNK(HSEL, TC0)                                                 \
        {                                                                    \
            const float4 hv4 = *(const float4*)&hring[HSEL][u_r][dc];        \
            float xr[4] = {hv4.x, hv4.y, hv4.z, hv4.w};                      \
            u16 rh[4], rl[4];                                                \
            _Pragma("unroll")                                                \
            for (int i = 0; i < 4; ++i) {                                    \
                rh[i] = f2bf_rne(xr[i]);                                     \
                rl[i] = f2bf_rne(xr[i] - bf2f(rh[i]));                       \
            }                                                                \
            ushort4 rhv = {rh[0], rh[1], rh[2], rh[3]};                      \
            ushort4 rlv = {rl[0], rl[1], rl[2], rl[3]};                      \
            *(ushort4*)&hhb[(size_t)((TC0) + u_r) * DD + dc] = rhv;          \
            *(ushort4*)&hlb[(size_t)((TC0) + u_r) * DD + dc] = rlv;          \
            u16 ch[4], cl[4];                                                \
            _Pragma("unroll")                                                \
            for (int j = 0; j < 4; ++j) {                                    \
                float x = hring[HSEL][ug + j][d_c];                          \
                ch[j] = f2bf_rne(x);                                         \
                cl[j] = f2bf_rne(x - bf2f(ch[j]));                           \
            }                                                                \
            ushort4 chv = {ch[0], ch[1], ch[2], ch[3]};                      \
            ushort4 clv = {cl[0], cl[1], cl[2], cl[3]};                      \
            *(ushort4*)&thb[(size_t)d_c * TT + (TC0) + ug] = chv;            \
            *(ushort4*)&tlb[(size_t)d_c * TT + (TC0) + ug] = clv;            \
        }

        {
            int id0 = idsb[0]; if ((unsigned)id0 >= VOCABN) id0 = 0;
            float ec = emb[id0 * DD + dd];
#pragma unroll
            for (int u = 0; u < UU; ++u) {
                float en = 0.f;
                if (u + 1 < UU) {
                    int idn = idsb[u + 1]; if ((unsigned)idn >= VOCABN) idn = 0;
                    en = emb[idn * DD + dd];
                }
                PROD_TOKEN(0, u, ec)
                ec = en;
            }
        }
        __syncthreads();
        int sel = 0;
        for (int t0 = 0; t0 < TT; t0 += UU) {
            if (t0 + UU < TT) {
                const int s = sel ^ 1;
                int id0 = idsb[t0 + UU]; if ((unsigned)id0 >= VOCABN) id0 = 0;
                float ec = emb[id0 * DD + dd];
#pragma unroll
                for (int u = 0; u < UU; ++u) {
                    float en = 0.f;
                    if (u + 1 < UU) {
                        int tn = t0 + UU + u + 1;
                        if (tn > TT - 1) tn = TT - 1;
                        int idn = idsb[tn]; if ((unsigned)idn >= VOCABN) idn = 0;
                        en = emb[idn * DD + dd];
                    }
                    PROD_TOKEN(s, u, ec)
                    ec = en;
                }
            }
            // cvt previous chunk (consumer wrote hring[(t0/UU-1)&1] before
            // the last barrier)
            if (t0) CVT_CHUNK((t0 / UU - 1) & 1, t0 - UU)
            __syncthreads();
            sel ^= 1;
        }
        // epilogue: convert the final chunk (written before the last barrier)
        CVT_CHUNK(1, TT - UU)
#undef PROD_TOKEN
#undef CVT_CHUNK
        return;
    }

    // ---------------- consumer: R19-exact scan + pk_fma dots ----------------
    const int d = l & 31;
    const bool hi = l >= 32;
    const int ga = (hi ? 32 : 0) + d;
    const int gb = (hi ? 96 : 64) + d;
    floatx2 rkp[DD];
#pragma unroll
    for (int k = 0; k < DD; ++k)
        rkp[k] = (floatx2){rk[k * GG + ga], rk[k * GG + gb]};

    float h = 0.0f, c = 0.0f;
    __syncthreads();   // matches producer prologue barrier
    int sel = 0;
    for (int t0 = 0; t0 < TT; t0 += UU) {
        float pa[UU], pb[UU];
#pragma unroll
        for (int u = 0; u < UU; ++u) {
            pa[u] = ring[sel][u][ga];
            pb[u] = ring[sel][u][gb];
        }
#pragma unroll
        for (int u = 0; u < UU; ++u) {
            floatx2 x0 = {pa[u], pb[u]};
            floatx2 x1 = {0.f, 0.f}, x2 = {0.f, 0.f}, x3 = {0.f, 0.f};
#pragma unroll
            for (int k = 0; k < DD; k += 4) {
                float h0 = readlane_f(h, k);
                float h1 = readlane_f(h, k + 1);
                float h2 = readlane_f(h, k + 2);
                float h3 = readlane_f(h, k + 3);
                x0 = fma2(h0, rkp[k],     x0);
                x1 = fma2(h1, rkp[k + 1], x1);
                x2 = fma2(h2, rkp[k + 2], x2);
                x3 = fma2(h3, rkp[k + 3], x3);
            }
            floatx2 zf = (x0 + x1) + (x2 + x3);
            float za = zf.x, zb = zf.y;
            float a = fsig(za);                       // sig(i) lo / sig(f) hi
            float zbm = hi ? zb : 2.0f * zb;
            float s2 = fsig(zbm);
            float bv = hi ? s2 : 2.0f * s2 - 1.0f;    // sig(o) hi / tanh(g) lo
            // lane<32 <-> lane+32 exchange via v_permlane32_swap_b32 (VALU).
            auto r1 = __builtin_amdgcn_permlane32_swap(
                __float_as_int(bv), __float_as_int(a), false, false);
            auto r2 = __builtin_amdgcn_permlane32_swap(
                __float_as_int(a), __float_as_int(bv), false, false);
            float fg = __int_as_float(r1[0]);
            float og = __int_as_float(r2[0]);
            c = fmaf(fg, c, a * bv);
            float tc = 2.0f * fsig(2.0f * c) - 1.0f;
            h = og * tc;
            if (!hi) hring[sel][u][d] = h;   // h ring for producer-side cvt
        }
        __syncthreads();
        sel ^= 1;
    }
}

// ---------------------------------------------------------------------------
// Kernel 3: attention — R32 = R31 core (verified 342.6 µs, absmax 0.0) +
// k_tail FUSED via last-block-per-batch reduction: each of the 4 blocks of a
// batch stores its 4 y-partials, threadfence, atomicAdd(ycnt[b]); the 4th
// arriver runs the verbatim tail (tid<256, LDS aliased over retired plds).
// Deletes the k_tail launch + gap. Tail arithmetic & partial order identical
// to R31 -> absmax unchanged.
// ---------------------------------------------------------------------------
__global__ __launch_bounds__(512, 1) void k_attn(const u16* __restrict__ hh,
                                                 const u16* __restrict__ hl,
                                                 const u16* __restrict__ th,
                                                 const u16* __restrict__ tl,
                                                 float* __restrict__ ypart,
                                                 int* __restrict__ ycnt,
                                                 const float* __restrict__ W1,
                                                 const float* __restrict__ b1,
                                                 const float* __restrict__ W2,
                                                 const float* __restrict__ b2,
                                                 float* __restrict__ out) {
    // layout (phase-overlaid, barriers separate):
    //  phase 1: plds, wave w at [w*10240, +10240) (4 tiles x 2 slots x 640 u16)
    //  phase 2: combine pairs at [p*13312, +13312) p=0..3 (64 lanes x 52 fl)
    //           ctile wave w<4 at [53248 + w*8704, +8704) (64x34 f32)
    //  phase 3 (tail, elected block only): ys at [0,4096), yr at [4096,+4224)
    __shared__ __align__(16) char smem[88064];
    __shared__ int elect;
    const int tid = threadIdx.x;
    const int w = tid >> 6;
    const int wt = w & 3;             // q-tile group
    const int kh = w >> 2;            // key half
    const int l = tid & 63;
    const int m = l & 15;
    const int g = l >> 4;
    const int b = blockIdx.x & 63;    // XCD swizzle: XCD = b % 8
    const int qt = (blockIdx.x >> 6) * 4 + wt;   // 0..15
    const int q0 = qt * 64;
    const int e0 = kh * 512;          // key element base for this wave
    const size_t rb = (size_t)b * TT * DD;
    const size_t tb = (size_t)b * DD * TT;
    u16* plw = (u16*)(smem + w * 10240);

    const short8 Qh0 = *(const short8*)&hh[rb + (size_t)(q0 + m) * DD + g * 8];
    const short8 Ql0 = *(const short8*)&hl[rb + (size_t)(q0 + m) * DD + g * 8];
    const short8 Qh1 = *(const short8*)&hh[rb + (size_t)(q0 + 16 + m) * DD + g * 8];
    const short8 Ql1 = *(const short8*)&hl[rb + (size_t)(q0 + 16 + m) * DD + g * 8];
    const short8 Qh2 = *(const short8*)&hh[rb + (size_t)(q0 + 32 + m) * DD + g * 8];
    const short8 Ql2 = *(const short8*)&hl[rb + (size_t)(q0 + 32 + m) * DD + g * 8];
    const short8 Qh3 = *(const short8*)&hh[rb + (size_t)(q0 + 48 + m) * DD + g * 8];
    const short8 Ql3 = *(const short8*)&hl[rb + (size_t)(q0 + 48 + m) * DD + g * 8];
    short8 ONES;
#pragma unroll
    for (int j = 0; j < 8; ++j) ONES[j] = (short)0x3F80;

    floatx4 c0 = {0.f, 0.f, 0.f, 0.f}, c1 = {0.f, 0.f, 0.f, 0.f};
    floatx4 c2 = {0.f, 0.f, 0.f, 0.f}, c3 = {0.f, 0.f, 0.f, 0.f};
    floatx4 c4 = {0.f, 0.f, 0.f, 0.f}, c5 = {0.f, 0.f, 0.f, 0.f};
    floatx4 c6 = {0.f, 0.f, 0.f, 0.f}, c7 = {0.f, 0.f, 0.f, 0.f};
    floatx4 la0 = {0.f, 0.f, 0.f, 0.f}, la1 = {0.f, 0.f, 0.f, 0.f};
    floatx4 la2 = {0.f, 0.f, 0.f, 0.f}, la3 = {0.f, 0.f, 0.f, 0.f};

#define S_BLOCK(QH, QL, KH_A, KL_A, KH_B, KL_B, SA, SB)                       \
    SA = __builtin_amdgcn_mfma_f32_16x16x32_bf16(QH, KH_A, SA, 0, 0, 0);      \
    SA = __builtin_amdgcn_mfma_f32_16x16x32_bf16(QH, KL_A, SA, 0, 0, 0);      \
    SA = __builtin_amdgcn_mfma_f32_16x16x32_bf16(QL, KH_A, SA, 0, 0, 0);      \
    SB = __builtin_amdgcn_mfma_f32_16x16x32_bf16(QH, KH_B, SB, 0, 0, 0);      \
    SB = __builtin_amdgcn_mfma_f32_16x16x32_bf16(QH, KL_B, SB, 0, 0, 0);      \
    SB = __builtin_amdgcn_mfma_f32_16x16x32_bf16(QL, KH_B, SB, 0, 0, 0);

#define EXP_STORE(SA, SB, TILE, SLOT)                                         \
    {                                                                         \
        u16* lp = plw + ((TILE) * 2 + (SLOT)) * 640;                          \
        _Pragma("unroll")                                                     \
        for (int r = 0; r < 4; ++r) {                                         \
            lp[(g * 4 + r) * 40 + m]      = f2bf_rne(__expf(SA[r]));          \
            lp[(g * 4 + r) * 40 + 16 + m] = f2bf_rne(__expf(SB[r]));          \
        }                                                                     \
    }

#define SPANEL(KhA, KlA, KhB, KlB, SLOT)                                      \
    {                                                                         \
        floatx4 sA = {0.f, 0.f, 0.f, 0.f}, sB = {0.f, 0.f, 0.f, 0.f};         \
        floatx4 tA = {0.f, 0.f, 0.f, 0.f}, tB = {0.f, 0.f, 0.f, 0.f};         \
        floatx4 uA = {0.f, 0.f, 0.f, 0.f}, uB = {0.f, 0.f, 0.f, 0.f};         \
        floatx4 vA = {0.f, 0.f, 0.f, 0.f}, vB = {0.f, 0.f, 0.f, 0.f};         \
        S_BLOCK(Qh0, Ql0, KhA, KlA, KhB, KlB, sA, sB)                         \
        S_BLOCK(Qh1, Ql1, KhA, KlA, KhB, KlB, tA, tB)                         \
        S_BLOCK(Qh2, Ql2, KhA, KlA, KhB, KlB, uA, uB)                         \
        S_BLOCK(Qh3, Ql3, KhA, KlA, KhB, KlB, vA, vB)                         \
        EXP_STORE(sA, sB, 0, SLOT)                                            \
        EXP_STORE(tA, tB, 1, SLOT)                                            \
        EXP_STORE(uA, uB, 2, SLOT)                                            \
        EXP_STORE(vA, vB, 3, SLOT)                                            \
    }

#define PV_TILE(T, CA, CB, LAc, SLOTP, VH0, VL0, VH1, VL1)                    \
    {                                                                         \
        const short8 P = *(const short8*)&plw[((T) * 2 + (SLOTP)) * 640 + m * 40 + g * 8]; \
        CA  = __builtin_amdgcn_mfma_f32_16x16x32_bf16(P, VH0, CA, 0, 0, 0);   \
        CA  = __builtin_amdgcn_mfma_f32_16x16x32_bf16(P, VL0, CA, 0, 0, 0);   \
        CB  = __builtin_amdgcn_mfma_f32_16x16x32_bf16(P, VH1, CB, 0, 0, 0);   \
        CB  = __builtin_amdgcn_mfma_f32_16x16x32_bf16(P, VL1, CB, 0, 0, 0);   \
        LAc = __builtin_amdgcn_mfma_f32_16x16x32_bf16(P, ONES, LAc, 0, 0, 0); \
    }

#define PV_PANEL(SLOTP, VH0, VL0, VH1, VL1)                                   \
    PV_TILE(0, c0, c1, la0, SLOTP, VH0, VL0, VH1, VL1)                        \
    PV_TILE(1, c2, c3, la1, SLOTP, VH0, VL0, VH1, VL1)                        \
    PV_TILE(2, c4, c5, la2, SLOTP, VH0, VL0, VH1, VL1)                        \
    PV_TILE(3, c6, c7, la3, SLOTP, VH0, VL0, VH1, VL1)

#define LOAD_K(BASE, RA, RLA, RB, RLB)                                        \
    RA  = *(const short8*)&hh[rb + (size_t)((BASE) + m) * DD + g * 8];        \
    RLA = *(const short8*)&hl[rb + (size_t)((BASE) + m) * DD + g * 8];        \
    RB  = *(const short8*)&hh[rb + (size_t)((BASE) + 16 + m) * DD + g * 8];   \
    RLB = *(const short8*)&hl[rb + (size_t)((BASE) + 16 + m) * DD + g * 8];

#define LOAD_V(BASE, RH0, RL0, RH1, RL1)                                      \
    RH0 = *(const short8*)&th[tb + (size_t)m * TT + (BASE) + g * 8];          \
    RL0 = *(const short8*)&tl[tb + (size_t)m * TT + (BASE) + g * 8];          \
    RH1 = *(const short8*)&th[tb + (size_t)(16 + m) * TT + (BASE) + g * 8];   \
    RL1 = *(const short8*)&tl[tb + (size_t)(16 + m) * TT + (BASE) + g * 8];

    // ---- prologue (j=0): S+exp for key-block e0 into slot 0 ----
    {
        short8 KA, KLA, KB, KLB;
        LOAD_K(e0, KA, KLA, KB, KLB)
        SPANEL(KA, KLA, KB, KLB, 0)
    }
    // preload V(e0) and K(e0+32)
    short8 Vh0, Vl0, Vh1, Vl1, KhA, KlA, KhB, KlB;
    LOAD_V(e0, Vh0, Vl0, Vh1, Vl1)
    LOAD_K(e0 + 32, KhA, KlA, KhB, KlB)

#pragma unroll 1
    for (int j = 1; j < 16; ++j) {
        const int knK = (j < 15) ? e0 + 32 * (j + 1) : 0;  // dummy tail
        const int knV = e0 + 32 * j;
        short8 nKhA, nKlA, nKhB, nKlB, nVh0, nVl0, nVh1, nVl1;
        LOAD_K(knK, nKhA, nKlA, nKhB, nKlB)
        LOAD_V(knV, nVh0, nVl0, nVh1, nVl1)

        SPANEL(KhA, KlA, KhB, KlB, j & 1)
        PV_PANEL((j - 1) & 1, Vh0, Vl0, Vh1, Vl1)

        KhA = nKhA; KlA = nKlA; KhB = nKhB; KlB = nKlB;
        Vh0 = nVh0; Vl0 = nVl0; Vh1 = nVh1; Vl1 = nVl1;
    }
    // epilogue: PV for j=15's S (slot 1), V(e0+480) rotated in
    PV_PANEL(1, Vh0, Vl0, Vh1, Vl1)
#undef S_BLOCK
#undef EXP_STORE
#undef SPANEL
#undef PV_TILE
#undef PV_PANEL
#undef LOAD_K

    // ---- combine the two key-halves (waves pair (wt), (wt+4)) ----
    __syncthreads();   // all plds reads done; combine region may alias plds
    if (w >= 4) {
        floatx4* dst = (floatx4*)(smem + wt * 13312 + l * 208);
        dst[0] = c0;  dst[1] = c1;  dst[2] = c2;  dst[3] = c3;
        dst[4] = c4;  dst[5] = c5;  dst[6] = c6;  dst[7] = c7;
        dst[8] = la0; dst[9] = la1; dst[10] = la2; dst[11] = la3;
    }
    __syncthreads();
    if (w < 4) {
        {
            const floatx4* src = (const floatx4*)(smem + wt * 13312 + l * 208);
            c0 += src[0];  c1 += src[1];  c2 += src[2];  c3 += src[3];
            c4 += src[4];  c5 += src[5];  c6 += src[6];  c7 += src[7];
            la0 += src[8]; la1 += src[9]; la2 += src[10]; la3 += src[11];
        }

        // ---- normalize into per-wave LDS transpose tile ct[t_local][d] ----
        float (*ct)[34] = (float (*)[34])(smem + 53248 + w * 8704);
#pragma unroll
        for (int r = 0; r < 4; ++r) {
            float li0 = __builtin_amdgcn_rcpf(la0[r]);
            float li1 = __builtin_amdgcn_rcpf(la1[r]);
            float li2 = __builtin_amdgcn_rcpf(la2[r]);
            float li3 = __builtin_amdgcn_rcpf(la3[r]);
            ct[g * 4 + r][m]            = c0[r] * li0;
            ct[g * 4 + r][16 + m]       = c1[r] * li0;
            ct[16 + g * 4 + r][m]       = c2[r] * li1;
            ct[16 + g * 4 + r][16 + m]  = c3[r] * li1;
            ct[32 + g * 4 + r][m]       = c4[r] * li2;
            ct[32 + g * 4 + r][16 + m]  = c5[r] * li2;
            ct[48 + g * 4 + r][m]       = c6[r] * li3;
            ct[48 + g * 4 + r][16 + m]  = c7[r] * li3;
        }
        // (same-wave LDS write->read below; no barrier needed)

        // ---- fused y-partial over this wave's 64 t-rows (R31-verified) ----
        floatx4 y00 = {0.f, 0.f, 0.f, 0.f}, y01 = {0.f, 0.f, 0.f, 0.f};
        floatx4 y10 = {0.f, 0.f, 0.f, 0.f}, y11 = {0.f, 0.f, 0.f, 0.f};
#pragma unroll
        for (int ch = 0; ch < 2; ++ch) {
            const int tloc = ch * 32 + g * 8;
            short8 A0h, A0l, A1h, A1l;
#pragma unroll
            for (int j = 0; j < 8; ++j) {
                float v0 = ct[tloc + j][m];
                u16 h0 = f2bf_rne(v0);
                A0h[j] = (short)h0;
                A0l[j] = (short)f2bf_rne(v0 - bf2f(h0));
                float v1 = ct[tloc + j][16 + m];
                u16 h1 = f2bf_rne(v1);
                A1h[j] = (short)h1;
                A1l[j] = (short)f2bf_rne(v1 - bf2f(h1));
            }
            short8 B0h, B0l, B1h, B1l;
            LOAD_V(q0 + ch * 32, B0h, B0l, B1h, B1l)
            y00 = __builtin_amdgcn_mfma_f32_16x16x32_bf16(A0h, B0h, y00, 0, 0, 0);
            y00 = __builtin_amdgcn_mfma_f32_16x16x32_bf16(A0h, B0l, y00, 0, 0, 0);
            y00 = __builtin_amdgcn_mfma_f32_16x16x32_bf16(A0l, B0h, y00, 0, 0, 0);
            y01 = __builtin_amdgcn_mfma_f32_16x16x32_bf16(A0h, B1h, y01, 0, 0, 0);
            y01 = __builtin_amdgcn_mfma_f32_16x16x32_bf16(A0h, B1l, y01, 0, 0, 0);
            y01 = __builtin_amdgcn_mfma_f32_16x16x32_bf16(A0l, B1h, y01, 0, 0, 0);
            y10 = __builtin_amdgcn_mfma_f32_16x16x32_bf16(A1h, B0h, y10, 0, 0, 0);
            y10 = __builtin_amdgcn_mfma_f32_16x16x32_bf16(A1h, B0l, y10, 0, 0, 0);
            y10 = __builtin_amdgcn_mfma_f32_16x16x32_bf16(A1l, B0h, y10, 0, 0, 0);
            y11 = __builtin_amdgcn_mfma_f32_16x16x32_bf16(A1h, B1h, y11, 0, 0, 0);
            y11 = __builtin_amdgcn_mfma_f32_16x16x32_bf16(A1h, B1l, y11, 0, 0, 0);
            y11 = __builtin_amdgcn_mfma_f32_16x16x32_bf16(A1l, B1h, y11, 0, 0, 0);
        }
        // store f32 partial: ypart[b][qt][d][e]  (D layout: col=m, row=g*4+r)
        float* yp = ypart + ((size_t)b * 16 + qt) * (DD * DD);
#pragma unroll
        for (int r = 0; r < 4; ++r) {
            yp[(g * 4 + r) * DD + m]            = y00[r];
            yp[(g * 4 + r) * DD + 16 + m]       = y01[r];
            yp[(16 + g * 4 + r) * DD + m]       = y10[r];
            yp[(16 + g * 4 + r) * DD + 16 + m]  = y11[r];
        }
        __threadfence();   // order ypart stores before the counter increment
    }
#undef LOAD_V

    // ---- last-block-per-batch election ----
    __syncthreads();
    if (tid == 0) {
        int old = atomicAdd(&ycnt[b], 1);
        elect = (old == 3) ? 1 : 0;
    }
    __syncthreads();
    if (!elect || tid >= 256) return;

    // ---- fused tail (verbatim R31 k_tail; ys/yr alias retired plds) ----
    __threadfence();   // acquire: partner blocks' ypart stores are visible
    float (*ys)[DD] = (float (*)[DD])smem;                    // 32x32 f32
    float (*yr)[DD + 1] = (float (*)[DD + 1])(smem + 4096);   // 32x33 f32
    const int e = tid & 31;
    const int d4 = (tid >> 5) * 4;
    const float* yb = ypart + (size_t)b * 16 * (DD * DD);
#pragma unroll
    for (int r = 0; r < 4; ++r) {
        float s = 0.f;
#pragma unroll
        for (int p = 0; p < 16; ++p)
            s += yb[p * (DD * DD) + (d4 + r) * DD + e];
        ys[d4 + r][e] = s;
    }
    __syncthreads();
#pragma unroll
    for (int r = 0; r < 4; ++r) {
        float v = b1[e];
#pragma unroll
        for (int ee = 0; ee < DD; ++ee) v += ys[d4 + r][ee] * W1[ee * DD + e];
        yr[d4 + r][e] = fmaxf(v, 0.0f);
    }
    __syncthreads();
    if (tid < DD) {
        float v = b2[0];
#pragma unroll
        for (int ee = 0; ee < DD; ++ee) v += yr[tid][ee] * W2[ee];
        out[b * DD + tid] = 1.0f / (1.0f + expf(-v));
    }
}

// ---------------------------------------------------------------------------
extern "C" void kernel_launch(void* const* d_in, const int* in_sizes, int n_in,
                              void* d_out, int out_size, void* d_ws, size_t ws_size,
                              hipStream_t stream) {
    const int* ids   = (const int*)d_in[0];
    const float* emb = (const float*)d_in[1];
    const float* kl  = (const float*)d_in[2];
    const float* rk  = (const float*)d_in[3];
    const float* bl  = (const float*)d_in[4];
    const float* W1  = (const float*)d_in[5];
    const float* b1  = (const float*)d_in[6];
    const float* W2  = (const float*)d_in[7];
    const float* b2  = (const float*)d_in[8];
    float* out = (float*)d_out;

    char* ws = (char*)d_ws;
    const size_t H_ELEMS = (size_t)BB * TT * DD;   // 2,097,152
    u16* hh   = (u16*)ws;
    u16* hl   = (u16*)(ws + H_ELEMS * 2);
    u16* th   = (u16*)(ws + H_ELEMS * 4);
    u16* tl   = (u16*)(ws + H_ELEMS * 6);
    float* ypart = (float*)(ws + H_ELEMS * 8);     // 64*16*1024 f32 = 4 MB
    int* ycnt = (int*)(ws + H_ELEMS * 8 + H_ELEMS * 2);   // 64 ints
    int* list = (int*)(ws + H_ELEMS * 8 + H_ELEMS * 8);

    k_lstm_scan<<<BB + 1, 128, 0, stream>>>(ids, emb, kl, bl, rk,
                                            hh, hl, th, tl, list, ycnt,
                                            out + BB * DD);
    k_attn<<<BB * 4, 512, 0, stream>>>(hh, hl, th, tl, ypart, ycnt,
                                       W1, b1, W2, b2, out);
}

// Round 16
// 341.360 us; speedup vs baseline: 1.0933x; 1.0933x over previous
//
#include <hip/hip_runtime.h>
#include <math.h>

#define BB 64
#define TT 1024
#define DD 32
#define GG 128   // 4*D
#define VOCABN 10000
#define QLEN 100

typedef short short8 __attribute__((ext_vector_type(8)));   // 8 bf16 in 4 VGPRs
typedef float floatx4 __attribute__((ext_vector_type(4)));
typedef float floatx2 __attribute__((ext_vector_type(2)));
typedef unsigned short u16;

__device__ __forceinline__ float fsig(float x) {
    return __builtin_amdgcn_rcpf(1.0f + __expf(-x));
}
__device__ __forceinline__ float readlane_f(float v, int l) {
    return __int_as_float(__builtin_amdgcn_readlane(__float_as_int(v), l));
}
__device__ __forceinline__ u16 f2bf_rne(float x) {
    unsigned u = __float_as_uint(x);
    u += 0x7FFF + ((u >> 16) & 1);
    return (u16)(u >> 16);
}
__device__ __forceinline__ float bf2f(u16 s) {
    return __uint_as_float(((unsigned)s) << 16);
}
// packed fma: one v_pk_fma_f32 for the {a,b}-gate pair. IEEE fma per half ->
// bit-exact vs two fmaf.
__device__ __forceinline__ floatx2 fma2(float s, floatx2 w, floatx2 acc) {
    return __builtin_elementwise_fma((floatx2){s, s}, w, acc);
}

// ---------------------------------------------------------------------------
// Kernel 1: LSTM scan — R28 version (measured 237 µs, VGPR 132). DO NOT
// reshape (R23/R24: any other shape spills the weight arrays). pk_fma dots +
// permlane32_swap + cvt fused into producer slack; hout stores deleted.
// ---------------------------------------------------------------------------
#define UU 8
__global__
__attribute__((amdgpu_flat_work_group_size(128, 128)))
__attribute__((amdgpu_waves_per_eu(1, 1)))
void k_lstm_scan(const int* __restrict__ ids,
                 const float* __restrict__ emb,
                 const float* __restrict__ klstm,
                 const float* __restrict__ bias,
                 const float* __restrict__ rk,
                 u16* __restrict__ hh, u16* __restrict__ hl,
                 u16* __restrict__ th, u16* __restrict__ tl,
                 int* __restrict__ list,
                 float* __restrict__ outq) {
    const int b = blockIdx.x;
    const int tid = threadIdx.x;
    const int wv = tid >> 6;   // wave 0 consumer / wave 1 producer+cvt
    const int l = tid & 63;
    if (b >= BB) {
        if (wv != 0) return;
        // ---- fused zero-index queue (single wave, no barriers) ----
        const int4* v4 = (const int4*)ids;
        const int C4 = (BB * TT) / 4 / 64;
        const int b4 = l * C4;
        int cnt = 0;
#pragma unroll 4
        for (int i = 0; i < C4; ++i) {
            int4 v = v4[b4 + i];
            cnt += (v.x == 0 || (unsigned)v.x >= VOCABN);
            cnt += (v.y == 0 || (unsigned)v.y >= VOCABN);
            cnt += (v.z == 0 || (unsigned)v.z >= VOCABN);
            cnt += (v.w == 0 || (unsigned)v.w >= VOCABN);
        }
        int scan = cnt;
#pragma unroll
        for (int o = 1; o < 64; o <<= 1) {
            int nn = __shfl_up(scan, o);
            if (l >= o) scan += nn;
        }
        const int total = __shfl(scan, 63);
        int off = scan - cnt;
        const int base = l * (C4 * 4);
#pragma unroll 4
        for (int i = 0; i < C4; ++i) {
            int4 v = v4[b4 + i];
            if (v.x == 0 || (unsigned)v.x >= VOCABN) list[off++] = base + 4 * i;
            if (v.y == 0 || (unsigned)v.y >= VOCABN) list[off++] = base + 4 * i + 1;
            if (v.z == 0 || (unsigned)v.z >= VOCABN) list[off++] = base + 4 * i + 2;
            if (v.w == 0 || (unsigned)v.w >= VOCABN) list[off++] = base + 4 * i + 3;
        }
        __threadfence();
        const int Kc = total < QLEN ? total : QLEN;
        for (int t = l; t < QLEN; t += 64) {
            float ii = -1.0f, jj = -1.0f;
            if (t >= QLEN - Kc) {
                int pos = list[total - QLEN + t];
                ii = (float)(pos >> 10);
                jj = (float)(pos & (TT - 1));
            }
            outq[2 * t] = ii;
            outq[2 * t + 1] = jj;
        }
        return;
    }

    __shared__ float ring[2][UU][GG];                    // 8 KB xg ring
    __shared__ __align__(16) float hring[2][UU][DD];     // 2 KB h ring (cvt)
    const int* idsb = ids + b * TT;

    if (wv == 1) {
        // ---------- producer: xg 8 tokens ahead + cvt of chunk-1 -----------
        const int ja = l, jb = l + 64;
        floatx2 kp[DD];
#pragma unroll
        for (int d2 = 0; d2 < DD; ++d2)
            kp[d2] = (floatx2){klstm[d2 * GG + ja], klstm[d2 * GG + jb]};
        const floatx2 bj = (floatx2){bias[ja], bias[jb]};
        const int dd = l & 31;
        // cvt lane mappings
        const int u_r = l >> 3, dc = (l & 7) * 4;        // row side: 8B u16 runs
        const int d_c = l & 31, ug = (l >> 5) * 4;       // col side: 4 consecutive t
        u16* hhb = hh + (size_t)b * TT * DD;
        u16* hlb = hl + (size_t)b * TT * DD;
        u16* thb = th + (size_t)b * DD * TT;
        u16* tlb = tl + (size_t)b * DD * TT;

#define PROD_TOKEN(SEL, U, EV)                                               \
        {                                                                    \
            floatx2 z0 = bj;                                                 \
            floatx2 z1 = {0.f, 0.f}, z2 = {0.f, 0.f}, z3 = {0.f, 0.f};       \
            _Pragma("unroll")                                                \
            for (int k = 0; k < DD; k += 4) {                                \
                float e0 = readlane_f(EV, k);                                \
                float e1 = readlane_f(EV, k + 1);                            \
                float e2 = readlane_f(EV, k + 2);                            \
                float e3 = readlane_f(EV, k + 3);                            \
                z0 = fma2(e0, kp[k], z0);                                    \
                z1 = fma2(e1, kp[k + 1], z1);                                \
                z2 = fma2(e2, kp[k + 2], z2);                                \
                z3 = fma2(e3, kp[k + 3], z3);                                \
            }                                                                \
            floatx2 zf = (z0 + z1) + (z2 + z3);                              \
            ring[SEL][U][ja] = zf.x;                                         \
            ring[SEL][U][jb] = zf.y;                                         \
        }

        // convert chunk starting at token TC0 from hring[HSEL]
#define CVT_CHUNK(HSEL, TC0)                                                 \
        {                                                                    \
            const float4 hv4 = *(const float4*)&hring[HSEL][u_r][dc];        \
            float xr[4] = {hv4.x, hv4.y, hv4.z, hv4.w};                      \
            u16 rh[4], rl[4];                                                \
            _Pragma("unroll")                                                \
            for (int i = 0; i < 4; ++i) {                                    \
                rh[i] = f2bf_rne(xr[i]);                                     \
                rl[i] = f2bf_rne(xr[i] - bf2f(rh[i]));                       \
            }                                                                \
            ushort4 rhv = {rh[0], rh[1], rh[2], rh[3]};                      \
            ushort4 rlv = {rl[0], rl[1], rl[2], rl[3]};                      \
            *(ushort4*)&hhb[(size_t)((TC0) + u_r) * DD + dc] = rhv;          \
            *(ushort4*)&hlb[(size_t)((TC0) + u_r) * DD + dc] = rlv;          \
            u16 ch[4], cl[4];                                                \
            _Pragma("unroll")                                                \
            for (int j = 0; j < 4; ++j) {                                    \
                float x = hring[HSEL][ug + j][d_c];                          \
                ch[j] = f2bf_rne(x);                                         \
                cl[j] = f2bf_rne(x - bf2f(ch[j]));                           \
            }                                                                \
            ushort4 chv = {ch[0], ch[1], ch[2], ch[3]};                      \
            ushort4 clv = {cl[0], cl[1], cl[2], cl[3]};                      \
            *(ushort4*)&thb[(size_t)d_c * TT + (TC0) + ug] = chv;            \
            *(ushort4*)&tlb[(size_t)d_c * TT + (TC0) + ug] = clv;            \
        }

        {
            int id0 = idsb[0]; if ((unsigned)id0 >= VOCABN) id0 = 0;
            float ec = emb[id0 * DD + dd];
#pragma unroll
            for (int u = 0; u < UU; ++u) {
                float en = 0.f;
                if (u + 1 < UU) {
                    int idn = idsb[u + 1]; if ((unsigned)idn >= VOCABN) idn = 0;
                    en = emb[idn * DD + dd];
                }
                PROD_TOKEN(0, u, ec)
                ec = en;
            }
        }
        __syncthreads();
        int sel = 0;
        for (int t0 = 0; t0 < TT; t0 += UU) {
            if (t0 + UU < TT) {
                const int s = sel ^ 1;
                int id0 = idsb[t0 + UU]; if ((unsigned)id0 >= VOCABN) id0 = 0;
                float ec = emb[id0 * DD + dd];
#pragma unroll
                for (int u = 0; u < UU; ++u) {
                    float en = 0.f;
                    if (u + 1 < UU) {
                        int tn = t0 + UU + u + 1;
                        if (tn > TT - 1) tn = TT - 1;
                        int idn = idsb[tn]; if ((unsigned)idn >= VOCABN) idn = 0;
                        en = emb[idn * DD + dd];
                    }
                    PROD_TOKEN(s, u, ec)
                    ec = en;
                }
            }
            // cvt previous chunk (consumer wrote hring[(t0/UU-1)&1] before
            // the last barrier)
            if (t0) CVT_CHUNK((t0 / UU - 1) & 1, t0 - UU)
            __syncthreads();
            sel ^= 1;
        }
        // epilogue: convert the final chunk (written before the last barrier)
        CVT_CHUNK(1, TT - UU)
#undef PROD_TOKEN
#undef CVT_CHUNK
        return;
    }

    // ---------------- consumer: R19-exact scan + pk_fma dots ----------------
    const int d = l & 31;
    const bool hi = l >= 32;
    const int ga = (hi ? 32 : 0) + d;
    const int gb = (hi ? 96 : 64) + d;
    floatx2 rkp[DD];
#pragma unroll
    for (int k = 0; k < DD; ++k)
        rkp[k] = (floatx2){rk[k * GG + ga], rk[k * GG + gb]};

    float h = 0.0f, c = 0.0f;
    __syncthreads();   // matches producer prologue barrier
    int sel = 0;
    for (int t0 = 0; t0 < TT; t0 += UU) {
        float pa[UU], pb[UU];
#pragma unroll
        for (int u = 0; u < UU; ++u) {
            pa[u] = ring[sel][u][ga];
            pb[u] = ring[sel][u][gb];
        }
#pragma unroll
        for (int u = 0; u < UU; ++u) {
            floatx2 x0 = {pa[u], pb[u]};
            floatx2 x1 = {0.f, 0.f}, x2 = {0.f, 0.f}, x3 = {0.f, 0.f};
#pragma unroll
            for (int k = 0; k < DD; k += 4) {
                float h0 = readlane_f(h, k);
                float h1 = readlane_f(h, k + 1);
                float h2 = readlane_f(h, k + 2);
                float h3 = readlane_f(h, k + 3);
                x0 = fma2(h0, rkp[k],     x0);
                x1 = fma2(h1, rkp[k + 1], x1);
                x2 = fma2(h2, rkp[k + 2], x2);
                x3 = fma2(h3, rkp[k + 3], x3);
            }
            floatx2 zf = (x0 + x1) + (x2 + x3);
            float za = zf.x, zb = zf.y;
            float a = fsig(za);                       // sig(i) lo / sig(f) hi
            float zbm = hi ? zb : 2.0f * zb;
            float s2 = fsig(zbm);
            float bv = hi ? s2 : 2.0f * s2 - 1.0f;    // sig(o) hi / tanh(g) lo
            // lane<32 <-> lane+32 exchange via v_permlane32_swap_b32 (VALU).
            auto r1 = __builtin_amdgcn_permlane32_swap(
                __float_as_int(bv), __float_as_int(a), false, false);
            auto r2 = __builtin_amdgcn_permlane32_swap(
                __float_as_int(a), __float_as_int(bv), false, false);
            float fg = __int_as_float(r1[0]);
            float og = __int_as_float(r2[0]);
            c = fmaf(fg, c, a * bv);
            float tc = 2.0f * fsig(2.0f * c) - 1.0f;
            h = og * tc;
            if (!hi) hring[sel][u][d] = h;   // h ring for producer-side cvt
        }
        __syncthreads();
        sel ^= 1;
    }
}

// ---------------------------------------------------------------------------
// Kernel 3: attention — R33 = R31 revert (verified 342.6 µs, absmax 0.0).
// R32's in-kernel last-block tail REGRESSED (+30 µs): device-scope fences on
// all 256 blocks + waves 4-7 kept resident + cross-XCD ypart reads cost far
// more than one tiny launch. Separate-launch reduction is the cheaper fence.
// R29 key-split core + fused y-partial; k_tail sums 16 partials.
// ---------------------------------------------------------------------------
__global__ __launch_bounds__(512, 1) void k_attn(const u16* __restrict__ hh,
                                                 const u16* __restrict__ hl,
                                                 const u16* __restrict__ th,
                                                 const u16* __restrict__ tl,
                                                 float* __restrict__ ypart) {
    // layout (phase-overlaid, barriers separate):
    //  phase 1: plds, wave w at [w*10240, +10240) (4 tiles x 2 slots x 640 u16)
    //  phase 2: combine pairs at [p*13312, +13312) p=0..3 (64 lanes x 52 fl)
    //           ctile wave w<4 at [53248 + w*8704, +8704) (64x34 f32)
    __shared__ __align__(16) char smem[88064];
    const int tid = threadIdx.x;
    const int w = tid >> 6;
    const int wt = w & 3;             // q-tile group
    const int kh = w >> 2;            // key half
    const int l = tid & 63;
    const int m = l & 15;
    const int g = l >> 4;
    const int b = blockIdx.x & 63;    // XCD swizzle: XCD = b % 8
    const int qt = (blockIdx.x >> 6) * 4 + wt;   // 0..15
    const int q0 = qt * 64;
    const int e0 = kh * 512;          // key element base for this wave
    const size_t rb = (size_t)b * TT * DD;
    const size_t tb = (size_t)b * DD * TT;
    u16* plw = (u16*)(smem + w * 10240);

    const short8 Qh0 = *(const short8*)&hh[rb + (size_t)(q0 + m) * DD + g * 8];
    const short8 Ql0 = *(const short8*)&hl[rb + (size_t)(q0 + m) * DD + g * 8];
    const short8 Qh1 = *(const short8*)&hh[rb + (size_t)(q0 + 16 + m) * DD + g * 8];
    const short8 Ql1 = *(const short8*)&hl[rb + (size_t)(q0 + 16 + m) * DD + g * 8];
    const short8 Qh2 = *(const short8*)&hh[rb + (size_t)(q0 + 32 + m) * DD + g * 8];
    const short8 Ql2 = *(const short8*)&hl[rb + (size_t)(q0 + 32 + m) * DD + g * 8];
    const short8 Qh3 = *(const short8*)&hh[rb + (size_t)(q0 + 48 + m) * DD + g * 8];
    const short8 Ql3 = *(const short8*)&hl[rb + (size_t)(q0 + 48 + m) * DD + g * 8];
    short8 ONES;
#pragma unroll
    for (int j = 0; j < 8; ++j) ONES[j] = (short)0x3F80;

    floatx4 c0 = {0.f, 0.f, 0.f, 0.f}, c1 = {0.f, 0.f, 0.f, 0.f};
    floatx4 c2 = {0.f, 0.f, 0.f, 0.f}, c3 = {0.f, 0.f, 0.f, 0.f};
    floatx4 c4 = {0.f, 0.f, 0.f, 0.f}, c5 = {0.f, 0.f, 0.f, 0.f};
    floatx4 c6 = {0.f, 0.f, 0.f, 0.f}, c7 = {0.f, 0.f, 0.f, 0.f};
    floatx4 la0 = {0.f, 0.f, 0.f, 0.f}, la1 = {0.f, 0.f, 0.f, 0.f};
    floatx4 la2 = {0.f, 0.f, 0.f, 0.f}, la3 = {0.f, 0.f, 0.f, 0.f};

#define S_BLOCK(QH, QL, KH_A, KL_A, KH_B, KL_B, SA, SB)                       \
    SA = __builtin_amdgcn_mfma_f32_16x16x32_bf16(QH, KH_A, SA, 0, 0, 0);      \
    SA = __builtin_amdgcn_mfma_f32_16x16x32_bf16(QH, KL_A, SA, 0, 0, 0);      \
    SA = __builtin_amdgcn_mfma_f32_16x16x32_bf16(QL, KH_A, SA, 0, 0, 0);      \
    SB = __builtin_amdgcn_mfma_f32_16x16x32_bf16(QH, KH_B, SB, 0, 0, 0);      \
    SB = __builtin_amdgcn_mfma_f32_16x16x32_bf16(QH, KL_B, SB, 0, 0, 0);      \
    SB = __builtin_amdgcn_mfma_f32_16x16x32_bf16(QL, KH_B, SB, 0, 0, 0);

#define EXP_STORE(SA, SB, TILE, SLOT)                                         \
    {                                                                         \
        u16* lp = plw + ((TILE) * 2 + (SLOT)) * 640;                          \
        _Pragma("unroll")                                                     \
        for (int r = 0; r < 4; ++r) {                                         \
            lp[(g * 4 + r) * 40 + m]      = f2bf_rne(__expf(SA[r]));          \
            lp[(g * 4 + r) * 40 + 16 + m] = f2bf_rne(__expf(SB[r]));          \
        }                                                                     \
    }

#define SPANEL(KhA, KlA, KhB, KlB, SLOT)                                      \
    {                                                                         \
        floatx4 sA = {0.f, 0.f, 0.f, 0.f}, sB = {0.f, 0.f, 0.f, 0.f};         \
        floatx4 tA = {0.f, 0.f, 0.f, 0.f}, tB = {0.f, 0.f, 0.f, 0.f};         \
        floatx4 uA = {0.f, 0.f, 0.f, 0.f}, uB = {0.f, 0.f, 0.f, 0.f};         \
        floatx4 vA = {0.f, 0.f, 0.f, 0.f}, vB = {0.f, 0.f, 0.f, 0.f};         \
        S_BLOCK(Qh0, Ql0, KhA, KlA, KhB, KlB, sA, sB)                         \
        S_BLOCK(Qh1, Ql1, KhA, KlA, KhB, KlB, tA, tB)                         \
        S_BLOCK(Qh2, Ql2, KhA, KlA, KhB, KlB, uA, uB)                         \
        S_BLOCK(Qh3, Ql3, KhA, KlA, KhB, KlB, vA, vB)                         \
        EXP_STORE(sA, sB, 0, SLOT)                                            \
        EXP_STORE(tA, tB, 1, SLOT)                                            \
        EXP_STORE(uA, uB, 2, SLOT)                                            \
        EXP_STORE(vA, vB, 3, SLOT)                                            \
    }

#define PV_TILE(T, CA, CB, LAc, SLOTP, VH0, VL0, VH1, VL1)                    \
    {                                                                         \
        const short8 P = *(const short8*)&plw[((T) * 2 + (SLOTP)) * 640 + m * 40 + g * 8]; \
        CA  = __builtin_amdgcn_mfma_f32_16x16x32_bf16(P, VH0, CA, 0, 0, 0);   \
        CA  = __builtin_amdgcn_mfma_f32_16x16x32_bf16(P, VL0, CA, 0, 0, 0);   \
        CB  = __builtin_amdgcn_mfma_f32_16x16x32_bf16(P, VH1, CB, 0, 0, 0);   \
        CB  = __builtin_amdgcn_mfma_f32_16x16x32_bf16(P, VL1, CB, 0, 0, 0);   \
        LAc = __builtin_amdgcn_mfma_f32_16x16x32_bf16(P, ONES, LAc, 0, 0, 0); \
    }

#define PV_PANEL(SLOTP, VH0, VL0, VH1, VL1)                                   \
    PV_TILE(0, c0, c1, la0, SLOTP, VH0, VL0, VH1, VL1)                        \
    PV_TILE(1, c2, c3, la1, SLOTP, VH0, VL0, VH1, VL1)                        \
    PV_TILE(2, c4, c5, la2, SLOTP, VH0, VL0, VH1, VL1)                        \
    PV_TILE(3, c6, c7, la3, SLOTP, VH0, VL0, VH1, VL1)

#define LOAD_K(BASE, RA, RLA, RB, RLB)                                        \
    RA  = *(const short8*)&hh[rb + (size_t)((BASE) + m) * DD + g * 8];        \
    RLA = *(const short8*)&hl[rb + (size_t)((BASE) + m) * DD + g * 8];        \
    RB  = *(const short8*)&hh[rb + (size_t)((BASE) + 16 + m) * DD + g * 8];   \
    RLB = *(const short8*)&hl[rb + (size_t)((BASE) + 16 + m) * DD + g * 8];

#define LOAD_V(BASE, RH0, RL0, RH1, RL1)                                      \
    RH0 = *(const short8*)&th[tb + (size_t)m * TT + (BASE) + g * 8];          \
    RL0 = *(const short8*)&tl[tb + (size_t)m * TT + (BASE) + g * 8];          \
    RH1 = *(const short8*)&th[tb + (size_t)(16 + m) * TT + (BASE) + g * 8];   \
    RL1 = *(const short8*)&tl[tb + (size_t)(16 + m) * TT + (BASE) + g * 8];

    // ---- prologue (j=0): S+exp for key-block e0 into slot 0 ----
    {
        short8 KA, KLA, KB, KLB;
        LOAD_K(e0, KA, KLA, KB, KLB)
        SPANEL(KA, KLA, KB, KLB, 0)
    }
    // preload V(e0) and K(e0+32)
    short8 Vh0, Vl0, Vh1, Vl1, KhA, KlA, KhB, KlB;
    LOAD_V(e0, Vh0, Vl0, Vh1, Vl1)
    LOAD_K(e0 + 32, KhA, KlA, KhB, KlB)

#pragma unroll 1
    for (int j = 1; j < 16; ++j) {
        const int knK = (j < 15) ? e0 + 32 * (j + 1) : 0;  // dummy tail
        const int knV = e0 + 32 * j;
        short8 nKhA, nKlA, nKhB, nKlB, nVh0, nVl0, nVh1, nVl1;
        LOAD_K(knK, nKhA, nKlA, nKhB, nKlB)
        LOAD_V(knV, nVh0, nVl0, nVh1, nVl1)

        SPANEL(KhA, KlA, KhB, KlB, j & 1)
        PV_PANEL((j - 1) & 1, Vh0, Vl0, Vh1, Vl1)

        KhA = nKhA; KlA = nKlA; KhB = nKhB; KlB = nKlB;
        Vh0 = nVh0; Vl0 = nVl0; Vh1 = nVh1; Vl1 = nVl1;
    }
    // epilogue: PV for j=15's S (slot 1), V(e0+480) rotated in
    PV_PANEL(1, Vh0, Vl0, Vh1, Vl1)
#undef S_BLOCK
#undef EXP_STORE
#undef SPANEL
#undef PV_TILE
#undef PV_PANEL
#undef LOAD_K

    // ---- combine the two key-halves (waves pair (wt), (wt+4)) ----
    __syncthreads();   // all plds reads done; combine region may alias plds
    if (w >= 4) {
        floatx4* dst = (floatx4*)(smem + wt * 13312 + l * 208);
        dst[0] = c0;  dst[1] = c1;  dst[2] = c2;  dst[3] = c3;
        dst[4] = c4;  dst[5] = c5;  dst[6] = c6;  dst[7] = c7;
        dst[8] = la0; dst[9] = la1; dst[10] = la2; dst[11] = la3;
    }
    __syncthreads();
    if (w >= 4) return;
    {
        const floatx4* src = (const floatx4*)(smem + wt * 13312 + l * 208);
        c0 += src[0];  c1 += src[1];  c2 += src[2];  c3 += src[3];
        c4 += src[4];  c5 += src[5];  c6 += src[6];  c7 += src[7];
        la0 += src[8]; la1 += src[9]; la2 += src[10]; la3 += src[11];
    }

    // ---- normalize into per-wave LDS transpose tile ct[t_local][d] ----
    float (*ct)[34] = (float (*)[34])(smem + 53248 + w * 8704);
#pragma unroll
    for (int r = 0; r < 4; ++r) {
        float li0 = __builtin_amdgcn_rcpf(la0[r]);
        float li1 = __builtin_amdgcn_rcpf(la1[r]);
        float li2 = __builtin_amdgcn_rcpf(la2[r]);
        float li3 = __builtin_amdgcn_rcpf(la3[r]);
        ct[g * 4 + r][m]            = c0[r] * li0;
        ct[g * 4 + r][16 + m]       = c1[r] * li0;
        ct[16 + g * 4 + r][m]       = c2[r] * li1;
        ct[16 + g * 4 + r][16 + m]  = c3[r] * li1;
        ct[32 + g * 4 + r][m]       = c4[r] * li2;
        ct[32 + g * 4 + r][16 + m]  = c5[r] * li2;
        ct[48 + g * 4 + r][m]       = c6[r] * li3;
        ct[48 + g * 4 + r][16 + m]  = c7[r] * li3;
    }
    // (same-wave LDS write->read below; no barrier needed)

    // ---- fused y-partial: y[d][e] += ctx[t][d]*h[t][e] over this wave's
    // 64 t-rows. A-frag (row=d via m, k=t via g*8+j) from ct with the same
    // f2bf hi/lo pair cth/ctl would have held; B-frag = th/tl fragments at
    // t = q0+chunk*32 (identical addressing to LOAD_V on this t range). ----
    floatx4 y00 = {0.f, 0.f, 0.f, 0.f}, y01 = {0.f, 0.f, 0.f, 0.f};
    floatx4 y10 = {0.f, 0.f, 0.f, 0.f}, y11 = {0.f, 0.f, 0.f, 0.f};
#pragma unroll
    for (int ch = 0; ch < 2; ++ch) {
        const int tloc = ch * 32 + g * 8;
        short8 A0h, A0l, A1h, A1l;
#pragma unroll
        for (int j = 0; j < 8; ++j) {
            float v0 = ct[tloc + j][m];
            u16 h0 = f2bf_rne(v0);
            A0h[j] = (short)h0;
            A0l[j] = (short)f2bf_rne(v0 - bf2f(h0));
            float v1 = ct[tloc + j][16 + m];
            u16 h1 = f2bf_rne(v1);
            A1h[j] = (short)h1;
            A1l[j] = (short)f2bf_rne(v1 - bf2f(h1));
        }
        short8 B0h, B0l, B1h, B1l;
        LOAD_V(q0 + ch * 32, B0h, B0l, B1h, B1l)
        y00 = __builtin_amdgcn_mfma_f32_16x16x32_bf16(A0h, B0h, y00, 0, 0, 0);
        y00 = __builtin_amdgcn_mfma_f32_16x16x32_bf16(A0h, B0l, y00, 0, 0, 0);
        y00 = __builtin_amdgcn_mfma_f32_16x16x32_bf16(A0l, B0h, y00, 0, 0, 0);
        y01 = __builtin_amdgcn_mfma_f32_16x16x32_bf16(A0h, B1h, y01, 0, 0, 0);
        y01 = __builtin_amdgcn_mfma_f32_16x16x32_bf16(A0h, B1l, y01, 0, 0, 0);
        y01 = __builtin_amdgcn_mfma_f32_16x16x32_bf16(A0l, B1h, y01, 0, 0, 0);
        y10 = __builtin_amdgcn_mfma_f32_16x16x32_bf16(A1h, B0h, y10, 0, 0, 0);
        y10 = __builtin_amdgcn_mfma_f32_16x16x32_bf16(A1h, B0l, y10, 0, 0, 0);
        y10 = __builtin_amdgcn_mfma_f32_16x16x32_bf16(A1l, B0h, y10, 0, 0, 0);
        y11 = __builtin_amdgcn_mfma_f32_16x16x32_bf16(A1h, B1h, y11, 0, 0, 0);
        y11 = __builtin_amdgcn_mfma_f32_16x16x32_bf16(A1h, B1l, y11, 0, 0, 0);
        y11 = __builtin_amdgcn_mfma_f32_16x16x32_bf16(A1l, B1h, y11, 0, 0, 0);
    }
#undef LOAD_V
    // store f32 partial: ypart[b][qt][d][e]  (D layout: col=m, row=g*4+r)
    float* yp = ypart + ((size_t)b * 16 + qt) * (DD * DD);
#pragma unroll
    for (int r = 0; r < 4; ++r) {
        yp[(g * 4 + r) * DD + m]            = y00[r];
        yp[(g * 4 + r) * DD + 16 + m]       = y01[r];
        yp[(16 + g * 4 + r) * DD + m]       = y10[r];
        yp[(16 + g * 4 + r) * DD + 16 + m]  = y11[r];
    }
}

// ---------------------------------------------------------------------------
// Kernel 4: k_tail — sum the 16 deterministic y-partials, then the existing
// (verified) W1/relu/W2/sigmoid tail verbatim.
// ---------------------------------------------------------------------------
__global__ __launch_bounds__(256) void k_tail(const float* __restrict__ ypart,
                                              const float* __restrict__ W1,
                                              const float* __restrict__ b1,
                                              const float* __restrict__ W2,
                                              const float* __restrict__ b2,
                                              float* __restrict__ out) {
    const int b = blockIdx.x;
    const int tid = threadIdx.x;
    const int e = tid & 31;
    const int d4 = (tid >> 5) * 4;
    const float* yb = ypart + (size_t)b * 16 * (DD * DD);
    __shared__ float ys[DD][DD];
#pragma unroll
    for (int r = 0; r < 4; ++r) {
        float s = 0.f;
#pragma unroll
        for (int p = 0; p < 16; ++p)
            s += yb[p * (DD * DD) + (d4 + r) * DD + e];
        ys[d4 + r][e] = s;
    }
    __syncthreads();
    __shared__ float yr[DD][33];
#pragma unroll
    for (int r = 0; r < 4; ++r) {
        float v = b1[e];
#pragma unroll
        for (int ee = 0; ee < DD; ++ee) v += ys[d4 + r][ee] * W1[ee * DD + e];
        yr[d4 + r][e] = fmaxf(v, 0.0f);
    }
    __syncthreads();
    if (tid < DD) {
        float v = b2[0];
#pragma unroll
        for (int ee = 0; ee < DD; ++ee) v += yr[tid][ee] * W2[ee];
        out[b * DD + tid] = 1.0f / (1.0f + expf(-v));
    }
}

// ---------------------------------------------------------------------------
extern "C" void kernel_launch(void* const* d_in, const int* in_sizes, int n_in,
                              void* d_out, int out_size, void* d_ws, size_t ws_size,
                              hipStream_t stream) {
    const int* ids   = (const int*)d_in[0];
    const float* emb = (const float*)d_in[1];
    const float* kl  = (const float*)d_in[2];
    const float* rk  = (const float*)d_in[3];
    const float* bl  = (const float*)d_in[4];
    const float* W1  = (const float*)d_in[5];
    const float* b1  = (const float*)d_in[6];
    const float* W2  = (const float*)d_in[7];
    const float* b2  = (const float*)d_in[8];
    float* out = (float*)d_out;

    char* ws = (char*)d_ws;
    const size_t H_ELEMS = (size_t)BB * TT * DD;   // 2,097,152
    u16* hh   = (u16*)ws;
    u16* hl   = (u16*)(ws + H_ELEMS * 2);
    u16* th   = (u16*)(ws + H_ELEMS * 4);
    u16* tl   = (u16*)(ws + H_ELEMS * 6);
    float* ypart = (float*)(ws + H_ELEMS * 8);     // 64*16*1024 f32 = 4 MB
    int* list = (int*)(ws + H_ELEMS * 8 + H_ELEMS * 8);

    k_lstm_scan<<<BB + 1, 128, 0, stream>>>(ids, emb, kl, bl, rk,
                                            hh, hl, th, tl, list, out + BB * DD);
    k_attn<<<BB * 4, 512, 0, stream>>>(hh, hl, th, tl, ypart);
    k_tail<<<BB, 256, 0, stream>>>(ypart, W1, b1, W2, b2, out);
}